// Round 2
// baseline (1427.250 us; speedup 1.0000x reference)
//
#include <hip/hip_runtime.h>
#include <cstdint>
#include <cstddef>

// R7: R5 split structure for k0/k1 (validated), but the 12 k2_step launches +
// k3 are fused into ONE persistent kernel (512 blocks, plain launch) with a
// hand-rolled device-scope ticket barrier (no hipLaunchCooperativeKernel --
// suspect in R6's failure). partial is double-buffered by step parity to kill
// the one structural cross-step race. 15 dispatches -> 3.

typedef __attribute__((ext_vector_type(8))) _Float16 f16x8;
typedef __attribute__((ext_vector_type(16))) float floatx16;

__device__ unsigned g_bar = 0;   // monotonic ticket counter, module lifetime.
                                 // Ticket barrier needs no reset across graph
                                 // replays: target = (ticket & ~511) + 512.

__device__ __forceinline__ float sigm_f(float v) { return 1.0f / (1.0f + __expf(-v)); }
__device__ __forceinline__ float tanh_f(float v) { return 2.0f / (1.0f + __expf(-2.0f * v)) - 1.0f; }

__device__ __forceinline__ void async16(void* lds, const void* g) {
    __builtin_amdgcn_global_load_lds(
        (const __attribute__((address_space(1))) void*)g,
        (__attribute__((address_space(3))) void*)lds, 16, 0, 0);
}

// Grid-wide barrier for EXACTLY 512 blocks. Release fence (L2 writeback) before
// arrival; relaxed agent-scope poll; acquire fence (cache inv) on exit by all
// threads so post-barrier vector loads / global_load_lds see remote writes.
__device__ __forceinline__ void grid_barrier512() {
    __syncthreads();                       // drains vmcnt: block's stores done
    if (threadIdx.x == 0) {
        __threadfence();                   // agent release: L2 writeback
        unsigned ticket = __hip_atomic_fetch_add(&g_bar, 1u, __ATOMIC_RELEASE,
                                                 __HIP_MEMORY_SCOPE_AGENT);
        unsigned target = (ticket & ~511u) + 512u;
        while (__hip_atomic_load(&g_bar, __ATOMIC_RELAXED,
                                 __HIP_MEMORY_SCOPE_AGENT) < target)
            __builtin_amdgcn_s_sleep(1);
    }
    __syncthreads();
    __threadfence();                       // agent acquire: invalidate stale lines
}

// ---------------- K0: casts + packing + a0 (unchanged from R5) ----------------
__global__ __launch_bounds__(256) void k0_prep(
    const float* __restrict__ z, const float* __restrict__ x,
    const float* __restrict__ x0, const float* __restrict__ W_ia,
    const float* __restrict__ b_ia, const float* __restrict__ W_ih,
    const float* __restrict__ W_hh, const float* __restrict__ W_h0,
    const float* __restrict__ W_out, const float* __restrict__ b_hh,
    _Float16* __restrict__ zx16, _Float16* __restrict__ wcat16,
    _Float16* __restrict__ whh16, float* __restrict__ pk, float* __restrict__ xbuf)
{
    const int ZX = 4096 * 256, WC = 2048 * 256, WH = 1536 * 512, PKN = 512, XB = 4096 * 2;
    const int total = ZX + WC + WH + PKN + XB;
    for (int idx = blockIdx.x * 256 + threadIdx.x; idx < total; idx += gridDim.x * 256) {
        if (idx < ZX) {
            int i = idx >> 8, k = idx & 255;
            float v = (k < 128) ? z[i * 128 + k] : x[i * 128 + (k - 128)];
            zx16[idx] = (_Float16)v;
        } else if (idx < ZX + WC) {
            int j = idx - ZX;
            int n = j >> 8, k = j & 255;
            float v = (n < 512) ? W_h0[n * 256 + k] : W_ih[(n - 512) * 258 + k];
            wcat16[j] = (_Float16)v;
        } else if (idx < ZX + WC + WH) {
            int j = idx - ZX - WC;
            whh16[j] = (_Float16)W_hh[j];
        } else if (idx < ZX + WC + WH + PKN) {
            int jc = idx - ZX - WC - WH;
            float* o = pk + jc * 12;
            o[0] = W_ih[jc * 258 + 256];          o[1] = W_ih[jc * 258 + 257];
            o[2] = W_ih[(512 + jc) * 258 + 256];  o[3] = W_ih[(512 + jc) * 258 + 257];
            o[4] = W_ih[(1024 + jc) * 258 + 256]; o[5] = W_ih[(1024 + jc) * 258 + 257];
            o[6] = b_hh[jc]; o[7] = b_hh[512 + jc]; o[8] = b_hh[1024 + jc];
            o[9] = W_out[jc]; o[10] = W_out[512 + jc]; o[11] = 0.f;
        } else {
            int j = idx - ZX - WC - WH - PKN;
            int i = j >> 1, d = j & 1;
            float s = b_ia[d];
            #pragma unroll
            for (int k2 = 0; k2 < 4; k2++) s += x0[i * 4 + k2] * W_ia[d * 4 + k2];
            xbuf[j] = s;
        }
    }
}

// ---------------- K1: h0 + gi planes (unchanged from R5) ----------------
__global__ __launch_bounds__(256) void k1_precompute(
    const _Float16* __restrict__ zx16, const _Float16* __restrict__ wcat16,
    const float* __restrict__ b_h0, const float* __restrict__ b_ih,
    _Float16* __restrict__ h16a, _Float16* __restrict__ gi16)
{
    __shared__ __align__(16) char smem[24576];
    const uint32_t BOFF = 0, AOFF = 8192;
    int tid = threadIdx.x;
    int w = tid >> 6, lane = tid & 63;
    int half = lane >> 5, l31 = lane & 31;
    int rsub = lane >> 3, csub = lane & 7;
    int Mb = blockIdx.x * 128, Nb = blockIdx.y * 64;

    const _Float16* gsrc[6];
    uint32_t ldso[6];
    #pragma unroll
    for (int j = 0; j < 6; j++) {
        int L = w + 4 * j;
        if (L < 16) {
            int r = L * 8 + rsub;
            gsrc[j] = zx16 + (size_t)(Mb + r) * 256 + ((csub ^ (r & 7)) << 3);
            ldso[j] = AOFF + (uint32_t)L * 1024;
        } else {
            int rb = (L - 16) * 8 + rsub;
            gsrc[j] = wcat16 + (size_t)(Nb + rb) * 256 + ((csub ^ (rb & 7)) << 3);
            ldso[j] = BOFF + (uint32_t)(L - 16) * 1024;
        }
    }

    floatx16 acc0 = {0,0,0,0,0,0,0,0,0,0,0,0,0,0,0,0};
    floatx16 acc1 = {0,0,0,0,0,0,0,0,0,0,0,0,0,0,0,0};

    for (int kc = 0; kc < 4; kc++) {
        #pragma unroll
        for (int j = 0; j < 6; j++) async16(smem + ldso[j], gsrc[j] + kc * 64);
        __syncthreads();
        #pragma unroll
        for (int ks = 0; ks < 4; ks++) {
            int ch = ks * 2 + half;
            int ar = (w << 5) | l31;
            f16x8 a = *(const f16x8*)(smem + AOFF + ((uint32_t)ar << 7) + ((uint32_t)(ch ^ (ar & 7)) << 4));
            uint32_t sw = (uint32_t)(ch ^ (l31 & 7)) << 4;
            f16x8 b0 = *(const f16x8*)(smem + BOFF + ((uint32_t)l31 << 7) + sw);
            f16x8 b1 = *(const f16x8*)(smem + BOFF + ((uint32_t)(32 + l31) << 7) + sw);
            acc0 = __builtin_amdgcn_mfma_f32_32x32x16_f16(a, b0, acc0, 0, 0, 0);
            acc1 = __builtin_amdgcn_mfma_f32_32x32x16_f16(a, b1, acc1, 0, 0, 0);
        }
        __syncthreads();
    }

    #pragma unroll
    for (int nt = 0; nt < 2; nt++) {
        int ncol = Nb + nt * 32 + l31;
        floatx16 acc = nt ? acc1 : acc0;
        #pragma unroll
        for (int reg = 0; reg < 16; reg++) {
            int row = (reg & 3) + 8 * (reg >> 2) + 4 * half;
            size_t i = (size_t)Mb + (w << 5) + row;
            float v = acc[reg];
            if (ncol < 512) {
                h16a[i * 512 + ncol] = (_Float16)(v + b_h0[ncol]);
            } else {
                int c = ncol - 512;
                int g = c >> 9, jc = c & 511;
                gi16[(size_t)g * 2097152 + i * 512 + jc] = (_Float16)(v + b_ih[c]);
            }
        }
    }
}

// ---------------- K2: persistent 12-step GRU + final output ----------------
// Exactly 512 blocks (bx=bid&31 -> 128 samples, by=bid>>5 -> 32 jc cols x 3
// gates). 46080 B LDS -> 3 blk/CU by LDS; launch_bounds(256,2) -> VGPR<=128
// -> >=2 blk/CU; 512 <= 256*2 so all blocks co-resident: barrier is safe.
__global__ __launch_bounds__(256, 2) void k2_persist(
    _Float16* __restrict__ h16a, _Float16* __restrict__ h16b,
    const _Float16* __restrict__ whh16, const _Float16* __restrict__ gi16,
    const float* __restrict__ pk, const float* __restrict__ xbuf,
    float* __restrict__ partial0, float* __restrict__ partial1,
    float* __restrict__ dout, const float* __restrict__ b_out)
{
    __shared__ __align__(16) char smem[46080];
    const uint32_t BOFF = 0, AOFF = 12288, PROD = 12288, XS = 45056;
    const int tid = threadIdx.x;
    const int bid = blockIdx.x;
    const int bx = bid & 31, by = bid >> 5;
    const int Mbase = bx * 128, Jbase = by * 32;
    const int w = tid >> 6, lane = tid & 63;
    const int half = lane >> 5, l31 = lane & 31;
    const int rsub = lane >> 3, csub = lane & 7;
    float* xs = (float*)(smem + XS);  // [128][2]

    // t-invariant epilogue state
    const int jcg = Jbase + l31;
    const float4* pkp = (const float4*)(pk + (size_t)jcg * 12);
    float4 p0 = pkp[0], p1 = pkp[1], p2 = pkp[2];
    // p0={wxr0,wxr1,wxz0,wxz1} p1={wxn0,wxn1,bhr,bhz} p2={bhn,wo0,wo1,-}
    const _Float16* giR = gi16;
    const _Float16* giZ = gi16 + 2097152;
    const _Float16* giN = gi16 + 4194304;

    #pragma unroll 1
    for (int t = 0; t < 12; t++) {
        const _Float16* hin = (t & 1) ? h16b : h16a;
        _Float16* hout = (t & 1) ? h16a : h16b;
        const float* pr = (t & 1) ? partial0 : partial1;   // written at t-1
        float* pw = (t & 1) ? partial1 : partial0;         // written at t

        const _Float16* gsrc[7];
        uint32_t ldso[7];
        #pragma unroll
        for (int j = 0; j < 7; j++) {
            int L = w + 4 * j;   // 0..27
            if (L < 16) {
                int r = L * 8 + rsub;
                gsrc[j] = hin + (size_t)(Mbase + r) * 512 + ((csub ^ (r & 7)) << 3);
                ldso[j] = AOFF + (uint32_t)L * 1024;
            } else {
                int rb = (L - 16) * 8 + rsub;   // 0..95: rb = g*32 + jin
                int g = rb >> 5, jin = rb & 31;
                gsrc[j] = whh16 + (size_t)(g * 512 + Jbase + jin) * 512 + ((csub ^ (rb & 7)) << 3);
                ldso[j] = BOFF + (uint32_t)(L - 16) * 1024;
            }
        }

        // prologue: x_t for this block's 128 samples (and write out_{t-1})
        {
            int i = tid >> 1, d = tid & 1;
            float v;
            if (t == 0) {
                v = xbuf[(size_t)(Mbase + i) * 2 + d];
            } else {
                const float4* p = (const float4*)(pr + ((size_t)(Mbase + i) * 2 + d) * 16);
                float4 a = p[0], b = p[1], c = p[2], e = p[3];
                v = b_out[d] + a.x + a.y + a.z + a.w + b.x + b.y + b.z + b.w
                             + c.x + c.y + c.z + c.w + e.x + e.y + e.z + e.w;
                if (by == 0) dout[((size_t)(Mbase + i) * 12 + (t - 1)) * 2 + d] = v;
            }
            xs[i * 2 + d] = v;
        }

        floatx16 accR = {0,0,0,0,0,0,0,0,0,0,0,0,0,0,0,0};
        floatx16 accZ = {0,0,0,0,0,0,0,0,0,0,0,0,0,0,0,0};
        floatx16 accN = {0,0,0,0,0,0,0,0,0,0,0,0,0,0,0,0};

        for (int kc = 0; kc < 8; kc++) {
            #pragma unroll
            for (int j = 0; j < 7; j++) async16(smem + ldso[j], gsrc[j] + kc * 64);
            __syncthreads();
            #pragma unroll
            for (int ks = 0; ks < 4; ks++) {
                int ch = ks * 2 + half;
                int ar = (w << 5) | l31;
                f16x8 a = *(const f16x8*)(smem + AOFF + ((uint32_t)ar << 7) + ((uint32_t)(ch ^ (ar & 7)) << 4));
                uint32_t sw = (uint32_t)(ch ^ (l31 & 7)) << 4;
                f16x8 b0 = *(const f16x8*)(smem + BOFF + ((uint32_t)l31 << 7) + sw);
                f16x8 b1 = *(const f16x8*)(smem + BOFF + ((uint32_t)(32 + l31) << 7) + sw);
                f16x8 b2 = *(const f16x8*)(smem + BOFF + ((uint32_t)(64 + l31) << 7) + sw);
                accR = __builtin_amdgcn_mfma_f32_32x32x16_f16(a, b0, accR, 0, 0, 0);
                accZ = __builtin_amdgcn_mfma_f32_32x32x16_f16(a, b1, accZ, 0, 0, 0);
                accN = __builtin_amdgcn_mfma_f32_32x32x16_f16(a, b2, accN, 0, 0, 0);
            }
            __syncthreads();
        }

        // epilogue: gates + state update; out-partials in LDS (reuse A region)
        float* prod = (float*)(smem + PROD);  // [128][32][2] fp32 = 32 KB
        #pragma unroll
        for (int reg = 0; reg < 16; reg++) {
            int row = (reg & 3) + 8 * (reg >> 2) + 4 * half;
            int iloc = (w << 5) + row;
            size_t i = (size_t)Mbase + iloc;
            float g0 = (float)giR[i * 512 + jcg];
            float g1 = (float)giZ[i * 512 + jcg];
            float g2v = (float)giN[i * 512 + jcg];
            float x0v = xs[iloc * 2], x1v = xs[iloc * 2 + 1];
            float r = sigm_f(g0 + p0.x * x0v + p0.y * x1v + accR[reg] + p1.z);
            float u = sigm_f(g1 + p0.z * x0v + p0.w * x1v + accZ[reg] + p1.w);
            float nn = tanh_f(g2v + p1.x * x0v + p1.y * x1v + r * (accN[reg] + p2.x));
            float hold = (float)hin[i * 512 + jcg];
            float hn = (1.f - u) * nn + u * hold;
            hout[i * 512 + jcg] = (_Float16)hn;
            ((float2*)prod)[iloc * 32 + l31] = make_float2(hn * p2.y, hn * p2.z);
        }
        __syncthreads();
        {
            int i = tid >> 1, d = tid & 1;
            float s = 0.f;
            #pragma unroll
            for (int jj = 0; jj < 32; jj++) {
                int jc = (jj + i) & 31;   // skew to avoid bank conflicts
                s += prod[(i * 32 + jc) * 2 + d];
            }
            pw[((size_t)(Mbase + i) * 2 + d) * 16 + by] = s;
        }
        grid_barrier512();
    }

    // final output out_11 (reads partial written at t=11 -> partial1)
    if (bid < 32) {
        int gid = bid * 256 + tid;
        int i = gid >> 1, d = gid & 1;
        const float4* p = (const float4*)(partial1 + ((size_t)i * 2 + d) * 16);
        float4 a = p[0], b = p[1], c = p[2], e = p[3];
        float v = b_out[d] + a.x + a.y + a.z + a.w + b.x + b.y + b.z + b.w
                           + c.x + c.y + c.z + c.w + e.x + e.y + e.z + e.w;
        dout[((size_t)i * 12 + 11) * 2 + d] = v;
    }
}

extern "C" void kernel_launch(void* const* d_in, const int* in_sizes, int n_in,
                              void* d_out, int out_size, void* d_ws, size_t ws_size,
                              hipStream_t stream)
{
    const float* z     = (const float*)d_in[0];
    const float* x     = (const float*)d_in[1];
    const float* x0    = (const float*)d_in[2];
    const float* W_ia  = (const float*)d_in[3];
    const float* b_ia  = (const float*)d_in[4];
    const float* W_h0  = (const float*)d_in[5];
    const float* b_h0  = (const float*)d_in[6];
    const float* W_ih  = (const float*)d_in[7];
    const float* b_ih  = (const float*)d_in[8];
    const float* W_hh  = (const float*)d_in[9];
    const float* b_hh  = (const float*)d_in[10];
    const float* W_out = (const float*)d_in[11];
    const float* b_out = (const float*)d_in[12];
    float* dout = (float*)d_out;

    char* ws = (char*)d_ws;
    _Float16* h16a   = (_Float16*)(ws + 0);          // 4 MiB
    _Float16* h16b   = (_Float16*)(ws + 4194304);    // 4 MiB
    _Float16* gi16   = (_Float16*)(ws + 8388608);    // 12 MiB
    _Float16* zx16   = (_Float16*)(ws + 20971520);   // 2 MiB (dead after k1;
                                                     //  tail reused as partial1)
    _Float16* wcat16 = (_Float16*)(ws + 23068672);   // 1 MiB
    _Float16* whh16  = (_Float16*)(ws + 24117248);   // 1.5 MiB
    float*    pk     = (float*)(ws + 25690112);      // 24 KiB
    float*    xbuf   = (float*)(ws + 25714688);      // 32 KiB
    float*    partial0 = (float*)(ws + 25747456);    // 512 KiB
    float*    partial1 = (float*)(ws + 20971520);    // overlays zx16 (dead after k1)

    k0_prep<<<2048, 256, 0, stream>>>(z, x, x0, W_ia, b_ia, W_ih, W_hh, W_h0,
                                      W_out, b_hh, zx16, wcat16, whh16, pk, xbuf);
    k1_precompute<<<dim3(32, 32), 256, 0, stream>>>(zx16, wcat16, b_h0, b_ih, h16a, gi16);
    k2_persist<<<512, 256, 0, stream>>>(h16a, h16b, whh16, gi16, pk, xbuf,
                                        partial0, partial1, dout, b_out);
}

// Round 3
// 496.882 us; speedup vs baseline: 2.8724x; 2.8724x over previous
//
#include <hip/hip_runtime.h>
#include <cstdint>
#include <cstddef>

// R8: fuse across TIME, not across the grid. k0/k1 identical to validated R5.
// k2_loop: 256 blocks x 1024 thr (16 waves, 1 block/CU). Each block owns 16
// samples and computes ALL 512 cols x 3 gates per step -> the 12-step GRU
// recurrence is block-local: no grid sync, no fences, L2 stays warm.
// h[16][512] fp16 lives in LDS (XOR-swizzled) across all steps. W_hh is
// streamed per K=32 chunk into a 96 KB LDS buffer via global_load_lds;
// staging is WAVE-PRIVATE (each wave stages/reads only its 32-jc rows), so
// the ks-loop needs no barriers -- only per-wave s_waitcnt. 3 launches total.

typedef __attribute__((ext_vector_type(8))) _Float16 f16x8;
typedef __attribute__((ext_vector_type(16))) float floatx16;
typedef __attribute__((ext_vector_type(4))) float floatx4;

__device__ __forceinline__ float sigm_f(float v) { return 1.0f / (1.0f + __expf(-v)); }
__device__ __forceinline__ float tanh_f(float v) { return 2.0f / (1.0f + __expf(-2.0f * v)) - 1.0f; }

__device__ __forceinline__ void async16(void* lds, const void* g) {
    __builtin_amdgcn_global_load_lds(
        (const __attribute__((address_space(1))) void*)g,
        (__attribute__((address_space(3))) void*)lds, 16, 0, 0);
}

// ---------------- K0: casts + packing + a0 (unchanged, validated) ----------------
__global__ __launch_bounds__(256) void k0_prep(
    const float* __restrict__ z, const float* __restrict__ x,
    const float* __restrict__ x0, const float* __restrict__ W_ia,
    const float* __restrict__ b_ia, const float* __restrict__ W_ih,
    const float* __restrict__ W_hh, const float* __restrict__ W_h0,
    const float* __restrict__ W_out, const float* __restrict__ b_hh,
    _Float16* __restrict__ zx16, _Float16* __restrict__ wcat16,
    _Float16* __restrict__ whh16, float* __restrict__ pk, float* __restrict__ xbuf)
{
    const int ZX = 4096 * 256, WC = 2048 * 256, WH = 1536 * 512, PKN = 512, XB = 4096 * 2;
    const int total = ZX + WC + WH + PKN + XB;
    for (int idx = blockIdx.x * 256 + threadIdx.x; idx < total; idx += gridDim.x * 256) {
        if (idx < ZX) {
            int i = idx >> 8, k = idx & 255;
            float v = (k < 128) ? z[i * 128 + k] : x[i * 128 + (k - 128)];
            zx16[idx] = (_Float16)v;
        } else if (idx < ZX + WC) {
            int j = idx - ZX;
            int n = j >> 8, k = j & 255;
            float v = (n < 512) ? W_h0[n * 256 + k] : W_ih[(n - 512) * 258 + k];
            wcat16[j] = (_Float16)v;
        } else if (idx < ZX + WC + WH) {
            int j = idx - ZX - WC;
            whh16[j] = (_Float16)W_hh[j];
        } else if (idx < ZX + WC + WH + PKN) {
            int jc = idx - ZX - WC - WH;
            float* o = pk + jc * 12;
            o[0] = W_ih[jc * 258 + 256];          o[1] = W_ih[jc * 258 + 257];
            o[2] = W_ih[(512 + jc) * 258 + 256];  o[3] = W_ih[(512 + jc) * 258 + 257];
            o[4] = W_ih[(1024 + jc) * 258 + 256]; o[5] = W_ih[(1024 + jc) * 258 + 257];
            o[6] = b_hh[jc]; o[7] = b_hh[512 + jc]; o[8] = b_hh[1024 + jc];
            o[9] = W_out[jc]; o[10] = W_out[512 + jc]; o[11] = 0.f;
        } else {
            int j = idx - ZX - WC - WH - PKN;
            int i = j >> 1, d = j & 1;
            float s = b_ia[d];
            #pragma unroll
            for (int k2 = 0; k2 < 4; k2++) s += x0[i * 4 + k2] * W_ia[d * 4 + k2];
            xbuf[j] = s;
        }
    }
}

// ---------------- K1: h0 + gi planes (unchanged, validated) ----------------
__global__ __launch_bounds__(256) void k1_precompute(
    const _Float16* __restrict__ zx16, const _Float16* __restrict__ wcat16,
    const float* __restrict__ b_h0, const float* __restrict__ b_ih,
    _Float16* __restrict__ h16a, _Float16* __restrict__ gi16)
{
    __shared__ __align__(16) char smem[24576];
    const uint32_t BOFF = 0, AOFF = 8192;
    int tid = threadIdx.x;
    int w = tid >> 6, lane = tid & 63;
    int half = lane >> 5, l31 = lane & 31;
    int rsub = lane >> 3, csub = lane & 7;
    int Mb = blockIdx.x * 128, Nb = blockIdx.y * 64;

    const _Float16* gsrc[6];
    uint32_t ldso[6];
    #pragma unroll
    for (int j = 0; j < 6; j++) {
        int L = w + 4 * j;
        if (L < 16) {
            int r = L * 8 + rsub;
            gsrc[j] = zx16 + (size_t)(Mb + r) * 256 + ((csub ^ (r & 7)) << 3);
            ldso[j] = AOFF + (uint32_t)L * 1024;
        } else {
            int rb = (L - 16) * 8 + rsub;
            gsrc[j] = wcat16 + (size_t)(Nb + rb) * 256 + ((csub ^ (rb & 7)) << 3);
            ldso[j] = BOFF + (uint32_t)(L - 16) * 1024;
        }
    }

    floatx16 acc0 = {0,0,0,0,0,0,0,0,0,0,0,0,0,0,0,0};
    floatx16 acc1 = {0,0,0,0,0,0,0,0,0,0,0,0,0,0,0,0};

    for (int kc = 0; kc < 4; kc++) {
        #pragma unroll
        for (int j = 0; j < 6; j++) async16(smem + ldso[j], gsrc[j] + kc * 64);
        __syncthreads();
        #pragma unroll
        for (int ks = 0; ks < 4; ks++) {
            int ch = ks * 2 + half;
            int ar = (w << 5) | l31;
            f16x8 a = *(const f16x8*)(smem + AOFF + ((uint32_t)ar << 7) + ((uint32_t)(ch ^ (ar & 7)) << 4));
            uint32_t sw = (uint32_t)(ch ^ (l31 & 7)) << 4;
            f16x8 b0 = *(const f16x8*)(smem + BOFF + ((uint32_t)l31 << 7) + sw);
            f16x8 b1 = *(const f16x8*)(smem + BOFF + ((uint32_t)(32 + l31) << 7) + sw);
            acc0 = __builtin_amdgcn_mfma_f32_32x32x16_f16(a, b0, acc0, 0, 0, 0);
            acc1 = __builtin_amdgcn_mfma_f32_32x32x16_f16(a, b1, acc1, 0, 0, 0);
        }
        __syncthreads();
    }

    #pragma unroll
    for (int nt = 0; nt < 2; nt++) {
        int ncol = Nb + nt * 32 + l31;
        floatx16 acc = nt ? acc1 : acc0;
        #pragma unroll
        for (int reg = 0; reg < 16; reg++) {
            int row = (reg & 3) + 8 * (reg >> 2) + 4 * half;
            size_t i = (size_t)Mb + (w << 5) + row;
            float v = acc[reg];
            if (ncol < 512) {
                h16a[i * 512 + ncol] = (_Float16)(v + b_h0[ncol]);
            } else {
                int c = ncol - 512;
                int g = c >> 9, jc = c & 511;
                gi16[(size_t)g * 2097152 + i * 512 + jc] = (_Float16)(v + b_ih[c]);
            }
        }
    }
}

// ---------------- K2: block-local 12-step GRU rollout ----------------
// 256 blocks x 1024 threads. Block owns samples [bid*16, bid*16+16).
// Wave wv owns jc in [wv*32, wv*32+32) -- its 96 weight rows (3 gates x 32)
// are staged into its private region of the B buffer; no cross-wave sharing.
// LDS: B stage [1536][32]h = 96 KB @0; h [16][512]h swizzled = 16 KB @98304;
//      xs [16][2]f @114688; oac [16][2]f @114816. Total 114944 (dynamic).
__global__ __launch_bounds__(1024) void k2_loop(
    const _Float16* __restrict__ h16a, const _Float16* __restrict__ whh16,
    const _Float16* __restrict__ gi16, const float* __restrict__ pk,
    const float* __restrict__ xbuf, const float* __restrict__ b_out,
    float* __restrict__ dout)
{
    extern __shared__ __align__(16) char smem[];
    const uint32_t BOFF = 0, HOFF = 98304, XSOFF = 114688, OAOFF = 114816;
    const int tid = threadIdx.x;
    const int bid = blockIdx.x;
    const int wv = tid >> 6;
    const int lane = tid & 63;
    const int l15 = lane & 15, q = lane >> 4;
    const int M0 = bid * 16;
    float* xs = (float*)(smem + XSOFF);
    float* oac = (float*)(smem + OAOFF);

    // ---- prologue: h0 -> LDS (swizzled); xs = a0; oac = 0 ----
    {
        int row = tid >> 6;           // 0..15
        int c8 = (tid & 63) * 8;      // 0..504
        f16x8 hv = *(const f16x8*)(h16a + (size_t)(M0 + row) * 512 + c8);
        uint32_t dst = HOFF + (uint32_t)row * 1024 +
                       (((uint32_t)(c8 * 2)) ^ (uint32_t)((row & 7) << 4));
        *(f16x8*)(smem + dst) = hv;
    }
    if (tid < 32) {
        int i = tid >> 1, d = tid & 1;
        xs[tid] = xbuf[(size_t)(M0 + i) * 2 + d];
        oac[tid] = 0.f;
    }

    // ---- t-invariant addresses ----
    const int jc0 = wv * 32;
    // B-fragment LDS read offsets (wave-private rows), constant across ks/t.
    uint32_t boffs[6];
    #pragma unroll
    for (int g = 0; g < 3; g++) {
        #pragma unroll
        for (int jt = 0; jt < 2; jt++) {
            int n = g * 512 + jc0 + jt * 16 + l15;
            boffs[g * 2 + jt] = BOFF + (uint32_t)n * 64 +
                                (uint32_t)((q ^ ((n >> 1) & 3)) << 4);
        }
    }
    // A-fragment base (h LDS, swizzled); per-ks address = abase ^ (ks*64).
    uint32_t abase = HOFF + (uint32_t)l15 * 1024 +
                     ((uint32_t)(q * 16) ^ (uint32_t)((l15 & 7) << 4));
    // Staging: 6 global_load_lds per wave per ks. LDS dest wave-uniform;
    // source pre-swizzled so linear lane*16 scatter lands bank-conflict-free.
    const _Float16* src[6];
    uint32_t sdst[6];
    #pragma unroll
    for (int j = 0; j < 6; j++) {
        int g = j >> 1, hf = j & 1;
        int rowbase = g * 512 + wv * 32 + hf * 16;   // wave-uniform
        sdst[j] = BOFF + (uint32_t)rowbase * 64;
        int nl = lane >> 2, s = lane & 3;
        int n = rowbase + nl;
        int qq = s ^ ((n >> 1) & 3);
        src[j] = whh16 + (size_t)n * 512 + qq * 8;
    }
    __syncthreads();

    #pragma unroll 1
    for (int t = 0; t < 12; t++) {
        floatx4 acc[6];
        #pragma unroll
        for (int j = 0; j < 6; j++) acc[j] = (floatx4){0.f, 0.f, 0.f, 0.f};

        // prime ks=0 stage
        #pragma unroll
        for (int j = 0; j < 6; j++) async16(smem + sdst[j], src[j]);

        #pragma unroll 1
        for (int ks = 0; ks < 16; ks++) {
            // DMA for this ks must have landed before we read it.
            asm volatile("s_waitcnt vmcnt(0)" ::: "memory");
            f16x8 av = *(const f16x8*)(smem + (abase ^ (uint32_t)(ks << 6)));
            f16x8 bv0 = *(const f16x8*)(smem + boffs[0]);
            f16x8 bv1 = *(const f16x8*)(smem + boffs[1]);
            f16x8 bv2 = *(const f16x8*)(smem + boffs[2]);
            f16x8 bv3 = *(const f16x8*)(smem + boffs[3]);
            f16x8 bv4 = *(const f16x8*)(smem + boffs[4]);
            f16x8 bv5 = *(const f16x8*)(smem + boffs[5]);
            // drain LDS reads, then it is safe to overwrite our region
            asm volatile("s_waitcnt lgkmcnt(0)" ::: "memory");
            if (ks < 15) {
                #pragma unroll
                for (int j = 0; j < 6; j++)
                    async16(smem + sdst[j], src[j] + (ks + 1) * 32);
            }
            acc[0] = __builtin_amdgcn_mfma_f32_16x16x32_f16(av, bv0, acc[0], 0, 0, 0);
            acc[1] = __builtin_amdgcn_mfma_f32_16x16x32_f16(av, bv1, acc[1], 0, 0, 0);
            acc[2] = __builtin_amdgcn_mfma_f32_16x16x32_f16(av, bv2, acc[2], 0, 0, 0);
            acc[3] = __builtin_amdgcn_mfma_f32_16x16x32_f16(av, bv3, acc[3], 0, 0, 0);
            acc[4] = __builtin_amdgcn_mfma_f32_16x16x32_f16(av, bv4, acc[4], 0, 0, 0);
            acc[5] = __builtin_amdgcn_mfma_f32_16x16x32_f16(av, bv5, acc[5], 0, 0, 0);
        }
        __syncthreads();   // all waves done reading h before epilogue writes it

        // ---- epilogue: gates, h update (in-place LDS), out partials ----
        float po[4][2];
        #pragma unroll
        for (int r2 = 0; r2 < 4; r2++) { po[r2][0] = 0.f; po[r2][1] = 0.f; }
        #pragma unroll
        for (int jt = 0; jt < 2; jt++) {
            int jc = jc0 + jt * 16 + l15;
            const float4* pkp = (const float4*)(pk + (size_t)jc * 12);
            float4 p0 = pkp[0], p1 = pkp[1], p2 = pkp[2];
            #pragma unroll
            for (int reg = 0; reg < 4; reg++) {
                int row = q * 4 + reg;                     // C: row=(lane>>4)*4+reg
                size_t ii = (size_t)(M0 + row);
                float g0  = (float)gi16[ii * 512 + jc];
                float g1  = (float)gi16[2097152 + ii * 512 + jc];
                float g2v = (float)gi16[4194304 + ii * 512 + jc];
                float x0v = xs[row * 2], x1v = xs[row * 2 + 1];
                uint32_t ha = HOFF + (uint32_t)row * 1024 +
                              (((uint32_t)(jc * 2)) ^ (uint32_t)((row & 7) << 4));
                float hold = (float)(*(const _Float16*)(smem + ha));
                float r  = sigm_f(g0 + p0.x * x0v + p0.y * x1v + acc[0 + jt][reg] + p1.z);
                float u  = sigm_f(g1 + p0.z * x0v + p0.w * x1v + acc[2 + jt][reg] + p1.w);
                float nn = tanh_f(g2v + p1.x * x0v + p1.y * x1v + r * (acc[4 + jt][reg] + p2.x));
                float hn = (1.f - u) * nn + u * hold;
                *(_Float16*)(smem + ha) = (_Float16)hn;
                po[reg][0] += hn * p2.y;
                po[reg][1] += hn * p2.z;
            }
        }
        // reduce over the 16 lanes sharing this row group, then one atomic
        #pragma unroll
        for (int m = 1; m < 16; m <<= 1) {
            #pragma unroll
            for (int reg = 0; reg < 4; reg++) {
                po[reg][0] += __shfl_xor(po[reg][0], m);
                po[reg][1] += __shfl_xor(po[reg][1], m);
            }
        }
        if (l15 == 0) {
            #pragma unroll
            for (int reg = 0; reg < 4; reg++) {
                atomicAdd(&oac[(q * 4 + reg) * 2 + 0], po[reg][0]);
                atomicAdd(&oac[(q * 4 + reg) * 2 + 1], po[reg][1]);
            }
        }
        __syncthreads();
        if (tid < 32) {
            int i = tid >> 1, d = tid & 1;
            float v = oac[tid] + b_out[d];
            dout[((size_t)(M0 + i) * 12 + t) * 2 + d] = v;
            xs[tid] = v;       // x_{t+1}
            oac[tid] = 0.f;
        }
        __syncthreads();
    }
}

extern "C" void kernel_launch(void* const* d_in, const int* in_sizes, int n_in,
                              void* d_out, int out_size, void* d_ws, size_t ws_size,
                              hipStream_t stream)
{
    const float* z     = (const float*)d_in[0];
    const float* x     = (const float*)d_in[1];
    const float* x0    = (const float*)d_in[2];
    const float* W_ia  = (const float*)d_in[3];
    const float* b_ia  = (const float*)d_in[4];
    const float* W_h0  = (const float*)d_in[5];
    const float* b_h0  = (const float*)d_in[6];
    const float* W_ih  = (const float*)d_in[7];
    const float* b_ih  = (const float*)d_in[8];
    const float* W_hh  = (const float*)d_in[9];
    const float* b_hh  = (const float*)d_in[10];
    const float* W_out = (const float*)d_in[11];
    const float* b_out = (const float*)d_in[12];
    float* dout = (float*)d_out;

    char* ws = (char*)d_ws;
    _Float16* h16a   = (_Float16*)(ws + 0);          // 4 MiB
    _Float16* gi16   = (_Float16*)(ws + 8388608);    // 12 MiB
    _Float16* zx16   = (_Float16*)(ws + 20971520);   // 2 MiB
    _Float16* wcat16 = (_Float16*)(ws + 23068672);   // 1 MiB
    _Float16* whh16  = (_Float16*)(ws + 24117248);   // 1.5 MiB
    float*    pk     = (float*)(ws + 25690112);      // 24 KiB
    float*    xbuf   = (float*)(ws + 25714688);      // 32 KiB

    static bool s_attr_done = false;
    if (!s_attr_done) {
        hipFuncSetAttribute((const void*)k2_loop,
                            hipFuncAttributeMaxDynamicSharedMemorySize, 114944);
        s_attr_done = true;
    }

    k0_prep<<<2048, 256, 0, stream>>>(z, x, x0, W_ia, b_ia, W_ih, W_hh, W_h0,
                                      W_out, b_hh, zx16, wcat16, whh16, pk, xbuf);
    k1_precompute<<<dim3(32, 32), 256, 0, stream>>>(zx16, wcat16, b_h0, b_ih, h16a, gi16);
    k2_loop<<<256, 1024, 114944, stream>>>(h16a, whh16, gi16, pk, xbuf, b_out, dout);
}